// Round 1
// baseline (738.538 us; speedup 1.0000x reference)
//
#include <hip/hip_runtime.h>
#include <hip/hip_bf16.h>

typedef __bf16 bf16x8 __attribute__((ext_vector_type(8)));
typedef float  f32x4  __attribute__((ext_vector_type(4)));

#define T_TOK 2048
#define DDIM  1024
#define EDIM  2048

// ---------------------------------------------------------------- transpose
// dst[(c*dmul + doff)*R + r] = op(src[r*S + c]);  R,C multiples of 32.
// OP 0: plain cast. OP 1: softplus(v + bias[c]) clipped to [1e-3, 0.1].
// OP 2: silu(v).
template<int OP, typename TS, typename TD>
__global__ __launch_bounds__(256)
void transpose_kernel(const TS* __restrict__ src, TD* __restrict__ dst,
                      int R, int C, int S, const float* __restrict__ bias,
                      int dmul, int doff)
{
    __shared__ float tile[32][33];
    const int tc0 = blockIdx.x * 32, tr0 = blockIdx.y * 32;
    const int tx = threadIdx.x & 31, ty = threadIdx.x >> 5;
#pragma unroll
    for (int p = 0; p < 4; ++p) {
        int rl = ty + p * 8;
        tile[rl][tx] = (float)src[(size_t)(tr0 + rl) * S + tc0 + tx];
    }
    __syncthreads();
#pragma unroll
    for (int p = 0; p < 4; ++p) {
        int cl = ty + p * 8;
        float v = tile[tx][cl];
        int c = tc0 + cl, r = tr0 + tx;
        if (OP == 1) {
            v += bias[c];
            v = (v > 20.f) ? v : log1pf(__expf(v));
            v = fminf(fmaxf(v, 0.001f), 0.1f);
        } else if (OP == 2) {
            v = v / (1.f + __expf(-v));
        }
        dst[((size_t)c * dmul + doff) * R + r] = (TD)v;
    }
}

// ---------------------------------------------------------------- rmsnorm
__global__ __launch_bounds__(256)
void rmsnorm_kernel(const float* __restrict__ x, const float* __restrict__ w,
                    __bf16* __restrict__ out)
{
    const int row = blockIdx.x;
    const int t = threadIdx.x;
    float4 v = ((const float4*)(x + (size_t)row * DDIM))[t];
    float ss = v.x * v.x + v.y * v.y + v.z * v.z + v.w * v.w;
#pragma unroll
    for (int m = 32; m; m >>= 1) ss += __shfl_xor(ss, m);
    __shared__ float red[4];
    if ((t & 63) == 0) red[t >> 6] = ss;
    __syncthreads();
    float scale = rsqrtf((red[0] + red[1] + red[2] + red[3]) * (1.f / DDIM) + 1e-5f);
    float4 wv = ((const float4*)w)[t];
    __bf16* o = out + (size_t)row * DDIM + t * 4;
    o[0] = (__bf16)(v.x * scale * wv.x);
    o[1] = (__bf16)(v.y * scale * wv.y);
    o[2] = (__bf16)(v.z * scale * wv.z);
    o[3] = (__bf16)(v.w * scale * wv.w);
}

// ---------------------------------------------------------------- conv+silu
__global__ __launch_bounds__(256)
void conv_silu_kernel(const __bf16* __restrict__ xp, const float* __restrict__ W,
                      const float* __restrict__ b, __bf16* __restrict__ xc)
{
    int idx = blockIdx.x * 256 + threadIdx.x;     // over T*E
    int t = idx >> 11, e = idx & (EDIM - 1);
    float s = b[e];
#pragma unroll
    for (int k = 0; k < 4; ++k) {                 // SAME pad: taps t-1..t+2
        int tt = t - 1 + k;
        if (tt >= 0 && tt < T_TOK)
            s += (float)xp[(size_t)tt * (2 * EDIM) + e] * W[k * EDIM + e];
    }
    s = s / (1.f + __expf(-s));
    xc[idx] = (__bf16)s;
}

// ---------------------------------------------------------------- glu
__global__ __launch_bounds__(256)
void glu_kernel(const __bf16* __restrict__ gu, __bf16* __restrict__ outm)
{
    int idx = blockIdx.x * 256 + threadIdx.x;     // over T*I
    int t = idx >> 11, i = idx & 2047;
    float g = (float)gu[(size_t)t * 4096 + i];
    float u = (float)gu[(size_t)t * 4096 + 2048 + i];
    outm[idx] = (__bf16)(g / (1.f + __expf(-g)) * u);
}

// ---------------------------------------------------------------- scan
template<int CTRL, int ROWMASK>
__device__ __forceinline__ float dpp_add(float v)
{
    int y = __builtin_amdgcn_update_dpp(0, __builtin_bit_cast(int, v),
                                        CTRL, ROWMASK, 0xf, true);
    return v + __builtin_bit_cast(float, y);
}

__global__ __launch_bounds__(256)
void scan_kernel(const float* __restrict__ dtT, const __bf16* __restrict__ xcT,
                 const __bf16* __restrict__ szT, const float* __restrict__ bc,
                 const float* __restrict__ A_log, __bf16* __restrict__ yT)
{
    const int lane = threadIdx.x & 63;
    const int wave = threadIdx.x >> 6;
    const int e = blockIdx.x * 4 + wave;
    const float An = -__expf(A_log[lane]);        // A[n] per lane
    const float* dtrow = dtT + (size_t)e * T_TOK;
    const __bf16* xrow = xcT + (size_t)e * T_TOK;
    const __bf16* zrow = szT + (size_t)e * T_TOK; // already silu'd
    __bf16* yrow = yT + (size_t)e * T_TOK;
    float h = 0.f, ysave = 0.f;
#pragma unroll 2
    for (int t = 0; t < T_TOK; ++t) {
        float dt = dtrow[t];
        float xv = (float)xrow[t];
        float2 bcv = ((const float2*)bc)[(size_t)t * 64 + lane]; // {B[n],C[n]}
        float dA = __expf(dt * An);
        h = fmaf(dt * xv, bcv.x, dA * h);
        float p = h * bcv.y;
        // wave-64 sum via DPP (VALU pipe), total lands in lane 63
        p = dpp_add<0x111, 0xf>(p);   // row_shr:1
        p = dpp_add<0x112, 0xf>(p);   // row_shr:2
        p = dpp_add<0x114, 0xf>(p);   // row_shr:4
        p = dpp_add<0x118, 0xf>(p);   // row_shr:8
        p = dpp_add<0x142, 0xa>(p);   // row_bcast:15 -> rows 1,3
        p = dpp_add<0x143, 0xc>(p);   // row_bcast:31 -> rows 2,3
        float tot = __builtin_bit_cast(float,
            __builtin_amdgcn_readlane(__builtin_bit_cast(int, p), 63));
        tot *= (float)zrow[t];        // gate with silu(z)
        ysave = ((t & 63) == lane) ? tot : ysave;
        if ((t & 63) == 63) yrow[(t - 63) + lane] = (__bf16)ysave;
    }
}

// ---------------------------------------------------------------- GEMM
// C[M,N] = A[M,K] @ Bt[N,K]^T.  M,N mult of 128, K mult of 32.
// EPI 0: f32 store. EPI 1: bf16 store. EPI 2: f32 store of acc + res.
template<int EPI>
__global__ __launch_bounds__(256)
void gemm_kernel(const __bf16* __restrict__ A, const __bf16* __restrict__ Bt,
                 void* __restrict__ Cout, const float* __restrict__ res,
                 int M, int N, int K)
{
    __shared__ bf16x8 sA[8 * 64];   // fragment-shuffled: [fm][lane] 16B each
    __shared__ bf16x8 sB[8 * 64];
    const int t = threadIdx.x;
    const int wave = t >> 6, lane = t & 63;
    const int brow = blockIdx.y * 128, bcol = blockIdx.x * 128;
    const int wr = (wave >> 1) * 64, wc = (wave & 1) * 64;
    f32x4 acc[4][4] = {};

    for (int k0 = 0; k0 < K; k0 += 32) {
        __syncthreads();
#pragma unroll
        for (int p = 0; p < 2; ++p) {
            int idx = (p * 256 + t) * 8;
            int r = idx >> 5;          // tile row 0..127
            int kk = idx & 31;         // 0,8,16,24
            bf16x8 va = *(const bf16x8*)(A + (size_t)(brow + r) * K + k0 + kk);
            bf16x8 vb = *(const bf16x8*)(Bt + (size_t)(bcol + r) * K + k0 + kk);
            int l = (r & 15) + (kk >> 3) * 16;   // dest lane within fragment
            sA[(r >> 4) * 64 + l] = va;
            sB[(r >> 4) * 64 + l] = vb;
        }
        __syncthreads();
        bf16x8 af[4], bg[4];
#pragma unroll
        for (int m = 0; m < 4; ++m) af[m] = sA[((wr >> 4) + m) * 64 + lane];
#pragma unroll
        for (int n = 0; n < 4; ++n) bg[n] = sB[((wc >> 4) + n) * 64 + lane];
#pragma unroll
        for (int m = 0; m < 4; ++m)
#pragma unroll
            for (int n = 0; n < 4; ++n)
                acc[m][n] = __builtin_amdgcn_mfma_f32_16x16x32_bf16(
                    af[m], bg[n], acc[m][n], 0, 0, 0);
    }

    const int c_l = lane & 15, r_l = (lane >> 4) * 4;
#pragma unroll
    for (int m = 0; m < 4; ++m) {
#pragma unroll
        for (int n = 0; n < 4; ++n) {
            int row = brow + wr + m * 16 + r_l;
            int col = bcol + wc + n * 16 + c_l;
#pragma unroll
            for (int i = 0; i < 4; ++i) {
                float v = acc[m][n][i];
                size_t off = (size_t)(row + i) * N + col;
                if (EPI == 0)      ((float*)Cout)[off] = v;
                else if (EPI == 1) ((__bf16*)Cout)[off] = (__bf16)v;
                else               ((float*)Cout)[off] = v + res[off];
            }
        }
    }
}

// ---------------------------------------------------------------- launch
extern "C" void kernel_launch(void* const* d_in, const int* in_sizes, int n_in,
                              void* d_out, int out_size, void* d_ws, size_t ws_size,
                              hipStream_t stream)
{
    (void)in_sizes; (void)n_in; (void)out_size; (void)ws_size;
    const float* x     = (const float*)d_in[0];
    const float* inw   = (const float*)d_in[1];
    const float* ffnw  = (const float*)d_in[2];
    const float* inpW  = (const float*)d_in[3];
    const float* convW = (const float*)d_in[4];
    const float* convB = (const float*)d_in[5];
    const float* dtW   = (const float*)d_in[6];
    const float* dtB   = (const float*)d_in[7];
    const float* BW    = (const float*)d_in[8];
    const float* CW    = (const float*)d_in[9];
    const float* Alog  = (const float*)d_in[10];
    const float* outpW = (const float*)d_in[11];
    const float* gateW = (const float*)d_in[12];
    const float* upW   = (const float*)d_in[13];
    const float* downW = (const float*)d_in[14];
    float* out = (float*)d_out;

    char* p = (char*)d_ws;
    auto alloc = [&](size_t n) { char* q = p; p += (n + 255) & ~(size_t)255; return q; };
    __bf16* wt_inproj = (__bf16*)alloc(4096ull * 1024 * 2);
    __bf16* wt_dt     = (__bf16*)alloc(2048ull * 2048 * 2);
    __bf16* wt_bc     = (__bf16*)alloc(128ull * 2048 * 2);   // interleaved B/C
    __bf16* wt_outp   = (__bf16*)alloc(1024ull * 2048 * 2);
    __bf16* wt_gu     = (__bf16*)alloc(4096ull * 1024 * 2);
    __bf16* wt_down   = (__bf16*)alloc(1024ull * 2048 * 2);
    __bf16* normed    = (__bf16*)alloc(2048ull * 1024 * 2);  // reused as n2
    __bf16* xp        = (__bf16*)alloc(2048ull * 4096 * 2);  // reused as gu
    __bf16* xc        = (__bf16*)alloc(2048ull * 2048 * 2);  // reused as y
    float*  dt_pre    = (float*)alloc(2048ull * 2048 * 4);   // reused as ffnmid
    float*  bc        = (float*)alloc(2048ull * 128 * 4);
    float*  dtT       = (float*)alloc(2048ull * 2048 * 4);
    __bf16* xcT       = (__bf16*)alloc(2048ull * 2048 * 2);
    __bf16* szT       = (__bf16*)alloc(2048ull * 2048 * 2);
    __bf16* yT        = (__bf16*)alloc(2048ull * 2048 * 2);
    float*  x2        = (float*)alloc(2048ull * 1024 * 4);

    dim3 B256(256);
    // weight prep (f32 -> bf16, transposed to [N][K])
    transpose_kernel<0, float, __bf16><<<dim3(128, 32), B256, 0, stream>>>(inpW, wt_inproj, 1024, 4096, 4096, nullptr, 1, 0);
    transpose_kernel<0, float, __bf16><<<dim3(64, 64), B256, 0, stream>>>(dtW, wt_dt, 2048, 2048, 2048, nullptr, 1, 0);
    transpose_kernel<0, float, __bf16><<<dim3(2, 64), B256, 0, stream>>>(BW, wt_bc, 2048, 64, 64, nullptr, 2, 0);
    transpose_kernel<0, float, __bf16><<<dim3(2, 64), B256, 0, stream>>>(CW, wt_bc, 2048, 64, 64, nullptr, 2, 1);
    transpose_kernel<0, float, __bf16><<<dim3(32, 64), B256, 0, stream>>>(outpW, wt_outp, 2048, 1024, 1024, nullptr, 1, 0);
    transpose_kernel<0, float, __bf16><<<dim3(64, 32), B256, 0, stream>>>(gateW, wt_gu, 1024, 2048, 2048, nullptr, 1, 0);
    transpose_kernel<0, float, __bf16><<<dim3(64, 32), B256, 0, stream>>>(upW, wt_gu + 2048ull * 1024, 1024, 2048, 2048, nullptr, 1, 0);
    transpose_kernel<0, float, __bf16><<<dim3(32, 64), B256, 0, stream>>>(downW, wt_down, 2048, 1024, 1024, nullptr, 1, 0);

    // normed = rmsnorm(x, inw)
    rmsnorm_kernel<<<dim3(2048), B256, 0, stream>>>(x, inw, normed);
    // xp = normed @ in_proj  (bf16)
    gemm_kernel<1><<<dim3(32, 16), B256, 0, stream>>>(normed, wt_inproj, xp, nullptr, 2048, 4096, 1024);
    // xc = silu(conv(xp[:, :E]) + b)
    conv_silu_kernel<<<dim3(T_TOK * EDIM / 256), B256, 0, stream>>>(xp, convW, convB, xc);
    // dt_pre = xc @ dt_W
    gemm_kernel<0><<<dim3(16, 16), B256, 0, stream>>>(xc, wt_dt, dt_pre, nullptr, 2048, 2048, 2048);
    // bc = xc @ [B|C interleaved]
    gemm_kernel<0><<<dim3(1, 16), B256, 0, stream>>>(xc, wt_bc, bc, nullptr, 2048, 128, 2048);
    // channel-major transposes for the scan
    transpose_kernel<1, float, float><<<dim3(64, 64), B256, 0, stream>>>(dt_pre, dtT, 2048, 2048, 2048, dtB, 1, 0);
    transpose_kernel<0, __bf16, __bf16><<<dim3(64, 64), B256, 0, stream>>>(xc, xcT, 2048, 2048, 2048, nullptr, 1, 0);
    transpose_kernel<2, __bf16, __bf16><<<dim3(64, 64), B256, 0, stream>>>(xp + 2048, szT, 2048, 2048, 4096, nullptr, 1, 0);
    // sequential SSM scan, gated by silu(z)
    scan_kernel<<<dim3(512), B256, 0, stream>>>(dtT, xcT, szT, bc, Alog, yT);
    // y = yT^T  (t-major, into xc buffer)
    __bf16* y = xc;
    transpose_kernel<0, __bf16, __bf16><<<dim3(64, 64), B256, 0, stream>>>(yT, y, 2048, 2048, 2048, nullptr, 1, 0);
    // x2 = x + y @ out_proj
    gemm_kernel<2><<<dim3(8, 16), B256, 0, stream>>>(y, wt_outp, x2, x, 2048, 1024, 2048);
    // n2 = rmsnorm(x2, ffnw)
    rmsnorm_kernel<<<dim3(2048), B256, 0, stream>>>(x2, ffnw, normed);
    // gu = n2 @ [gate|up]
    __bf16* gu = xp;
    gemm_kernel<1><<<dim3(32, 16), B256, 0, stream>>>(normed, wt_gu, gu, nullptr, 2048, 4096, 1024);
    // ffnmid = silu(gate)*up
    __bf16* ffnmid = (__bf16*)dt_pre;
    glu_kernel<<<dim3(T_TOK * 2048 / 256), B256, 0, stream>>>(gu, ffnmid);
    // out = x2 + ffnmid @ down
    gemm_kernel<2><<<dim3(8, 16), B256, 0, stream>>>(ffnmid, wt_down, out, x2, 2048, 1024, 2048);
}

// Round 2
// 604.149 us; speedup vs baseline: 1.2224x; 1.2224x over previous
//
#include <hip/hip_runtime.h>
#include <hip/hip_bf16.h>

typedef __bf16 bf16x8 __attribute__((ext_vector_type(8)));
typedef float  f32x4  __attribute__((ext_vector_type(4)));

#define T_TOK 2048
#define DDIM  1024
#define EDIM  2048
#define NCHUNK 8
#define CKLEN  256

// ---------------------------------------------------------------- transpose
// dst[(c*dmul + doff)*R + r] = op(src[r*S + c]);  R,C multiples of 32.
// OP 0: plain cast. OP 1: softplus(v + bias[c]) clipped to [1e-3, 0.1].
// OP 2: silu(v).
template<int OP, typename TS, typename TD>
__global__ __launch_bounds__(256)
void transpose_kernel(const TS* __restrict__ src, TD* __restrict__ dst,
                      int R, int C, int S, const float* __restrict__ bias,
                      int dmul, int doff)
{
    __shared__ float tile[32][33];
    const int tc0 = blockIdx.x * 32, tr0 = blockIdx.y * 32;
    const int tx = threadIdx.x & 31, ty = threadIdx.x >> 5;
#pragma unroll
    for (int p = 0; p < 4; ++p) {
        int rl = ty + p * 8;
        tile[rl][tx] = (float)src[(size_t)(tr0 + rl) * S + tc0 + tx];
    }
    __syncthreads();
#pragma unroll
    for (int p = 0; p < 4; ++p) {
        int cl = ty + p * 8;
        float v = tile[tx][cl];
        int c = tc0 + cl, r = tr0 + tx;
        if (OP == 1) {
            v += bias[c];
            v = (v > 20.f) ? v : log1pf(__expf(v));
            v = fminf(fmaxf(v, 0.001f), 0.1f);
        } else if (OP == 2) {
            v = v / (1.f + __expf(-v));
        }
        dst[((size_t)c * dmul + doff) * R + r] = (TD)v;
    }
}

// ---------------------------------------------------------------- rmsnorm
__global__ __launch_bounds__(256)
void rmsnorm_kernel(const float* __restrict__ x, const float* __restrict__ w,
                    __bf16* __restrict__ out)
{
    const int row = blockIdx.x;
    const int t = threadIdx.x;
    float4 v = ((const float4*)(x + (size_t)row * DDIM))[t];
    float ss = v.x * v.x + v.y * v.y + v.z * v.z + v.w * v.w;
#pragma unroll
    for (int m = 32; m; m >>= 1) ss += __shfl_xor(ss, m);
    __shared__ float red[4];
    if ((t & 63) == 0) red[t >> 6] = ss;
    __syncthreads();
    float scale = rsqrtf((red[0] + red[1] + red[2] + red[3]) * (1.f / DDIM) + 1e-5f);
    float4 wv = ((const float4*)w)[t];
    __bf16* o = out + (size_t)row * DDIM + t * 4;
    o[0] = (__bf16)(v.x * scale * wv.x);
    o[1] = (__bf16)(v.y * scale * wv.y);
    o[2] = (__bf16)(v.z * scale * wv.z);
    o[3] = (__bf16)(v.w * scale * wv.w);
}

// ---------------------------------------------------------------- conv+silu
__global__ __launch_bounds__(256)
void conv_silu_kernel(const __bf16* __restrict__ xp, const float* __restrict__ W,
                      const float* __restrict__ b, __bf16* __restrict__ xc)
{
    int idx = blockIdx.x * 256 + threadIdx.x;     // over T*E
    int t = idx >> 11, e = idx & (EDIM - 1);
    float s = b[e];
#pragma unroll
    for (int k = 0; k < 4; ++k) {                 // SAME pad: taps t-1..t+2
        int tt = t - 1 + k;
        if (tt >= 0 && tt < T_TOK)
            s += (float)xp[(size_t)tt * (2 * EDIM) + e] * W[k * EDIM + e];
    }
    s = s / (1.f + __expf(-s));
    xc[idx] = (__bf16)s;
}

// ---------------------------------------------------------------- glu
__global__ __launch_bounds__(256)
void glu_kernel(const __bf16* __restrict__ gu, __bf16* __restrict__ outm)
{
    int idx = blockIdx.x * 256 + threadIdx.x;     // over T*I
    int t = idx >> 11, i = idx & 2047;
    float g = (float)gu[(size_t)t * 4096 + i];
    float u = (float)gu[(size_t)t * 4096 + 2048 + i];
    outm[idx] = (__bf16)(g / (1.f + __expf(-g)) * u);
}

// ---------------------------------------------------------------- scan
template<int CTRL, int ROWMASK>
__device__ __forceinline__ float dpp_add(float v)
{
    int y = __builtin_amdgcn_update_dpp(0, __builtin_bit_cast(int, v),
                                        CTRL, ROWMASK, 0xf, true);
    return v + __builtin_bit_cast(float, y);
}

// Pass 1: per (e,chunk) compute local h_end (h0=0) and P = prod(dA).
// bc layout: bc[t*128 + n] = B, bc[t*128 + 64 + n] = C.
__global__ __launch_bounds__(256)
void scan1_kernel(const float* __restrict__ dtT, const __bf16* __restrict__ xcT,
                  const float* __restrict__ bc, const float* __restrict__ A_log,
                  float* __restrict__ hend, float* __restrict__ dAp)
{
    const int lane = threadIdx.x & 63, wave = threadIdx.x >> 6;
    const int ck = blockIdx.x & (NCHUNK - 1);
    const int e  = (blockIdx.x >> 3) * 4 + wave;
    const float An = -__expf(A_log[lane]);
    const float*  dtrow = dtT + (size_t)e * T_TOK + ck * CKLEN;
    const __bf16* xrow  = xcT + (size_t)e * T_TOK + ck * CKLEN;
    const float*  bcp   = bc + (size_t)(ck * CKLEN) * 128 + lane;
    float h = 0.f, P = 1.f;
    for (int t0 = 0; t0 < CKLEN; t0 += 8) {
        float4 da = *(const float4*)(dtrow + t0);
        float4 db = *(const float4*)(dtrow + t0 + 4);
        bf16x8 x8 = *(const bf16x8*)(xrow + t0);
        float dtv[8] = {da.x, da.y, da.z, da.w, db.x, db.y, db.z, db.w};
#pragma unroll
        for (int j = 0; j < 8; ++j) {
            float Bv = bcp[(t0 + j) * 128];
            float dA = __expf(dtv[j] * An);
            h = fmaf(dA, h, dtv[j] * (float)x8[j] * Bv);
            P *= dA;
        }
    }
    hend[((size_t)e * NCHUNK + ck) * 64 + lane] = h;
    dAp [((size_t)e * NCHUNK + ck) * 64 + lane] = P;
}

// Mid: serial scan over the 8 chunk summaries -> true h_start per chunk.
__global__ __launch_bounds__(256)
void scan_mid_kernel(const float* __restrict__ hend, const float* __restrict__ dAp,
                     float* __restrict__ h0)
{
    int gid = blockIdx.x * 256 + threadIdx.x;     // over E*64
    int e = gid >> 6, n = gid & 63;
    float h = 0.f;
#pragma unroll
    for (int ck = 0; ck < NCHUNK; ++ck) {
        size_t idx = ((size_t)e * NCHUNK + ck) * 64 + n;
        h0[idx] = h;
        h = dAp[idx] * h + hend[idx];
    }
}

// Pass 2: re-run each chunk from its true h_start, emit y (gated by silu(z)).
__global__ __launch_bounds__(256)
void scan2_kernel(const float* __restrict__ dtT, const __bf16* __restrict__ xcT,
                  const __bf16* __restrict__ szT, const float* __restrict__ bc,
                  const float* __restrict__ A_log, const float* __restrict__ h0,
                  __bf16* __restrict__ yT)
{
    const int lane = threadIdx.x & 63, wave = threadIdx.x >> 6;
    const int ck = blockIdx.x & (NCHUNK - 1);
    const int e  = (blockIdx.x >> 3) * 4 + wave;
    const float An = -__expf(A_log[lane]);
    const size_t base = (size_t)e * T_TOK + ck * CKLEN;
    const float*  dtrow = dtT + base;
    const __bf16* xrow  = xcT + base;
    const __bf16* zrow  = szT + base;
    __bf16*       yrow  = yT + base;
    const float*  bcp   = bc + (size_t)(ck * CKLEN) * 128;
    float h = h0[((size_t)e * NCHUNK + ck) * 64 + lane];
    float ysave = 0.f;
    for (int t0 = 0; t0 < CKLEN; t0 += 8) {
        float4 da = *(const float4*)(dtrow + t0);
        float4 db = *(const float4*)(dtrow + t0 + 4);
        bf16x8 x8 = *(const bf16x8*)(xrow + t0);
        bf16x8 z8 = *(const bf16x8*)(zrow + t0);
        float dtv[8] = {da.x, da.y, da.z, da.w, db.x, db.y, db.z, db.w};
#pragma unroll
        for (int j = 0; j < 8; ++j) {
            int t = t0 + j;
            float Bv = bcp[t * 128 + lane];
            float Cv = bcp[t * 128 + 64 + lane];
            float dA = __expf(dtv[j] * An);
            h = fmaf(dA, h, dtv[j] * (float)x8[j] * Bv);
            float p = h * Cv;
            p = dpp_add<0x111, 0xf>(p);   // row_shr:1
            p = dpp_add<0x112, 0xf>(p);   // row_shr:2
            p = dpp_add<0x114, 0xf>(p);   // row_shr:4
            p = dpp_add<0x118, 0xf>(p);   // row_shr:8
            p = dpp_add<0x142, 0xa>(p);   // row_bcast:15 -> rows 1,3
            p = dpp_add<0x143, 0xc>(p);   // row_bcast:31 -> rows 2,3
            float tot = __builtin_bit_cast(float,
                __builtin_amdgcn_readlane(__builtin_bit_cast(int, p), 63));
            tot *= (float)z8[j];          // gate with silu(z)
            ysave = ((t & 63) == lane) ? tot : ysave;
            if ((t & 63) == 63) yrow[(t - 63) + lane] = (__bf16)ysave;
        }
    }
}

// ---------------------------------------------------------------- GEMM
// C[M,N] = A[M,K] @ Bt[N,K]^T.  M,N mult of 128, K mult of 32.
// EPI 0: f32 store. EPI 1: bf16 store. EPI 2: f32 store of acc + res.
template<int EPI>
__global__ __launch_bounds__(256)
void gemm_kernel(const __bf16* __restrict__ A, const __bf16* __restrict__ Bt,
                 void* __restrict__ Cout, const float* __restrict__ res,
                 int M, int N, int K)
{
    __shared__ bf16x8 sA[8 * 64];   // fragment-shuffled: [fm][lane] 16B each
    __shared__ bf16x8 sB[8 * 64];
    const int t = threadIdx.x;
    const int wave = t >> 6, lane = t & 63;
    const int brow = blockIdx.y * 128, bcol = blockIdx.x * 128;
    const int wr = (wave >> 1) * 64, wc = (wave & 1) * 64;
    f32x4 acc[4][4] = {};

    for (int k0 = 0; k0 < K; k0 += 32) {
        __syncthreads();
#pragma unroll
        for (int p = 0; p < 2; ++p) {
            int idx = (p * 256 + t) * 8;
            int r = idx >> 5;          // tile row 0..127
            int kk = idx & 31;         // 0,8,16,24
            bf16x8 va = *(const bf16x8*)(A + (size_t)(brow + r) * K + k0 + kk);
            bf16x8 vb = *(const bf16x8*)(Bt + (size_t)(bcol + r) * K + k0 + kk);
            int l = (r & 15) + (kk >> 3) * 16;   // dest lane within fragment
            sA[(r >> 4) * 64 + l] = va;
            sB[(r >> 4) * 64 + l] = vb;
        }
        __syncthreads();
        bf16x8 af[4], bg[4];
#pragma unroll
        for (int m = 0; m < 4; ++m) af[m] = sA[((wr >> 4) + m) * 64 + lane];
#pragma unroll
        for (int n = 0; n < 4; ++n) bg[n] = sB[((wc >> 4) + n) * 64 + lane];
#pragma unroll
        for (int m = 0; m < 4; ++m)
#pragma unroll
            for (int n = 0; n < 4; ++n)
                acc[m][n] = __builtin_amdgcn_mfma_f32_16x16x32_bf16(
                    af[m], bg[n], acc[m][n], 0, 0, 0);
    }

    const int c_l = lane & 15, r_l = (lane >> 4) * 4;
#pragma unroll
    for (int m = 0; m < 4; ++m) {
#pragma unroll
        for (int n = 0; n < 4; ++n) {
            int row = brow + wr + m * 16 + r_l;
            int col = bcol + wc + n * 16 + c_l;
#pragma unroll
            for (int i = 0; i < 4; ++i) {
                float v = acc[m][n][i];
                size_t off = (size_t)(row + i) * N + col;
                if (EPI == 0)      ((float*)Cout)[off] = v;
                else if (EPI == 1) ((__bf16*)Cout)[off] = (__bf16)v;
                else               ((float*)Cout)[off] = v + res[off];
            }
        }
    }
}

// ---------------------------------------------------------------- launch
extern "C" void kernel_launch(void* const* d_in, const int* in_sizes, int n_in,
                              void* d_out, int out_size, void* d_ws, size_t ws_size,
                              hipStream_t stream)
{
    (void)in_sizes; (void)n_in; (void)out_size; (void)ws_size;
    const float* x     = (const float*)d_in[0];
    const float* inw   = (const float*)d_in[1];
    const float* ffnw  = (const float*)d_in[2];
    const float* inpW  = (const float*)d_in[3];
    const float* convW = (const float*)d_in[4];
    const float* convB = (const float*)d_in[5];
    const float* dtW   = (const float*)d_in[6];
    const float* dtB   = (const float*)d_in[7];
    const float* BW    = (const float*)d_in[8];
    const float* CW    = (const float*)d_in[9];
    const float* Alog  = (const float*)d_in[10];
    const float* outpW = (const float*)d_in[11];
    const float* gateW = (const float*)d_in[12];
    const float* upW   = (const float*)d_in[13];
    const float* downW = (const float*)d_in[14];
    float* out = (float*)d_out;

    char* p = (char*)d_ws;
    auto alloc = [&](size_t n) { char* q = p; p += (n + 255) & ~(size_t)255; return q; };
    __bf16* wt_inproj = (__bf16*)alloc(4096ull * 1024 * 2);
    __bf16* wt_dt     = (__bf16*)alloc(2048ull * 2048 * 2);
    __bf16* wt_bc     = (__bf16*)alloc(128ull * 2048 * 2);   // rows 0-63 = B, 64-127 = C
    __bf16* wt_outp   = (__bf16*)alloc(1024ull * 2048 * 2);
    __bf16* wt_gu     = (__bf16*)alloc(4096ull * 1024 * 2);
    __bf16* wt_down   = (__bf16*)alloc(1024ull * 2048 * 2);
    __bf16* normed    = (__bf16*)alloc(2048ull * 1024 * 2);  // reused as n2
    __bf16* xp        = (__bf16*)alloc(2048ull * 4096 * 2);  // reused as gu
    __bf16* xc        = (__bf16*)alloc(2048ull * 2048 * 2);  // reused as y
    float*  dt_pre    = (float*)alloc(2048ull * 2048 * 4);   // reused: chunk state + ffnmid
    float*  bc        = (float*)alloc(2048ull * 128 * 4);
    float*  dtT       = (float*)alloc(2048ull * 2048 * 4);
    __bf16* xcT       = (__bf16*)alloc(2048ull * 2048 * 2);
    __bf16* szT       = (__bf16*)alloc(2048ull * 2048 * 2);
    __bf16* yT        = (__bf16*)alloc(2048ull * 2048 * 2);
    float*  x2        = (float*)alloc(2048ull * 1024 * 4);

    dim3 B256(256);
    // weight prep (f32 -> bf16, transposed to [N][K])
    transpose_kernel<0, float, __bf16><<<dim3(128, 32), B256, 0, stream>>>(inpW, wt_inproj, 1024, 4096, 4096, nullptr, 1, 0);
    transpose_kernel<0, float, __bf16><<<dim3(64, 64), B256, 0, stream>>>(dtW, wt_dt, 2048, 2048, 2048, nullptr, 1, 0);
    transpose_kernel<0, float, __bf16><<<dim3(2, 64), B256, 0, stream>>>(BW, wt_bc, 2048, 64, 64, nullptr, 1, 0);
    transpose_kernel<0, float, __bf16><<<dim3(2, 64), B256, 0, stream>>>(CW, wt_bc, 2048, 64, 64, nullptr, 1, 64);
    transpose_kernel<0, float, __bf16><<<dim3(32, 64), B256, 0, stream>>>(outpW, wt_outp, 2048, 1024, 1024, nullptr, 1, 0);
    transpose_kernel<0, float, __bf16><<<dim3(64, 32), B256, 0, stream>>>(gateW, wt_gu, 1024, 2048, 2048, nullptr, 1, 0);
    transpose_kernel<0, float, __bf16><<<dim3(64, 32), B256, 0, stream>>>(upW, wt_gu + 2048ull * 1024, 1024, 2048, 2048, nullptr, 1, 0);
    transpose_kernel<0, float, __bf16><<<dim3(32, 64), B256, 0, stream>>>(downW, wt_down, 2048, 1024, 1024, nullptr, 1, 0);

    // normed = rmsnorm(x, inw)
    rmsnorm_kernel<<<dim3(2048), B256, 0, stream>>>(x, inw, normed);
    // xp = normed @ in_proj  (bf16)
    gemm_kernel<1><<<dim3(32, 16), B256, 0, stream>>>(normed, wt_inproj, xp, nullptr, 2048, 4096, 1024);
    // xc = silu(conv(xp[:, :E]) + b)
    conv_silu_kernel<<<dim3(T_TOK * EDIM / 256), B256, 0, stream>>>(xp, convW, convB, xc);
    // dt_pre = xc @ dt_W
    gemm_kernel<0><<<dim3(16, 16), B256, 0, stream>>>(xc, wt_dt, dt_pre, nullptr, 2048, 2048, 2048);
    // bc = xc @ [B|C]  (bc[t][0:64]=B, bc[t][64:128]=C)
    gemm_kernel<0><<<dim3(1, 16), B256, 0, stream>>>(xc, wt_bc, bc, nullptr, 2048, 128, 2048);
    // channel-major transposes for the scan
    transpose_kernel<1, float, float><<<dim3(64, 64), B256, 0, stream>>>(dt_pre, dtT, 2048, 2048, 2048, dtB, 1, 0);
    transpose_kernel<0, __bf16, __bf16><<<dim3(64, 64), B256, 0, stream>>>(xc, xcT, 2048, 2048, 2048, nullptr, 1, 0);
    transpose_kernel<2, __bf16, __bf16><<<dim3(64, 64), B256, 0, stream>>>(xp + 2048, szT, 2048, 2048, 4096, nullptr, 1, 0);

    // chunked SSM scan: dt_pre region is free now (dtT holds softplus'd dt)
    float* hend = dt_pre;                         // 4 MB
    float* dAp  = dt_pre + 2048ull * 8 * 64;      // 4 MB
    float* h0   = dt_pre + 2048ull * 8 * 64 * 2;  // 4 MB
    scan1_kernel<<<dim3(4096), B256, 0, stream>>>(dtT, xcT, bc, Alog, hend, dAp);
    scan_mid_kernel<<<dim3(512), B256, 0, stream>>>(hend, dAp, h0);
    scan2_kernel<<<dim3(4096), B256, 0, stream>>>(dtT, xcT, szT, bc, Alog, h0, yT);

    // y = yT^T  (t-major, into xc buffer)
    __bf16* y = xc;
    transpose_kernel<0, __bf16, __bf16><<<dim3(64, 64), B256, 0, stream>>>(yT, y, 2048, 2048, 2048, nullptr, 1, 0);
    // x2 = x + y @ out_proj
    gemm_kernel<2><<<dim3(8, 16), B256, 0, stream>>>(y, wt_outp, x2, x, 2048, 1024, 2048);
    // n2 = rmsnorm(x2, ffnw)
    rmsnorm_kernel<<<dim3(2048), B256, 0, stream>>>(x2, ffnw, normed);
    // gu = n2 @ [gate|up]
    __bf16* gu = xp;
    gemm_kernel<1><<<dim3(32, 16), B256, 0, stream>>>(normed, wt_gu, gu, nullptr, 2048, 4096, 1024);
    // ffnmid = silu(gate)*up
    __bf16* ffnmid = (__bf16*)dt_pre;
    glu_kernel<<<dim3(T_TOK * 2048 / 256), B256, 0, stream>>>(gu, ffnmid);
    // out = x2 + ffnmid @ down
    gemm_kernel<2><<<dim3(8, 16), B256, 0, stream>>>(ffnmid, wt_down, out, x2, 2048, 1024, 2048);
}